// Round 17
// baseline (124.142 us; speedup 1.0000x reference)
//
#include <hip/hip_runtime.h>
#include <stdint.h>

// Problem constants
#define T_  4096
#define B_  64
#define DI_ 64
#define DH_ 512
#define DO_ 64
#define L_  64          // chunk length
#define C_  (T_ / L_)   // 64 chunks

typedef __attribute__((ext_vector_type(8))) short bf16x8;
typedef __attribute__((ext_vector_type(2))) float f32x2;
typedef __attribute__((ext_vector_type(4))) float f32x4;
typedef __attribute__((ext_vector_type(8))) float f32x8;
typedef __attribute__((ext_vector_type(2))) __bf16 bfv2;
typedef __attribute__((ext_vector_type(8))) __bf16 bfv8;

union U8 { uint4 q; bf16x8 v; bfv8 b; };
union U2 { unsigned u; bfv2 b; };

__device__ inline unsigned short f2b_rne(float f) {
    unsigned u = __float_as_uint(f);
    return (unsigned short)((u + 0x7fffu + ((u >> 16) & 1u)) >> 16);
}

// trunc-split 8 f32 -> hi bf16x8 + lo bf16x8 (combined rel err ~2^-16)
__device__ inline void trunc_split8(const float4 v0, const float4 v1, U8& hi, U8& lo) {
    const unsigned u0 = __float_as_uint(v0.x), u1 = __float_as_uint(v0.y),
                   u2 = __float_as_uint(v0.z), u3 = __float_as_uint(v0.w),
                   u4 = __float_as_uint(v1.x), u5 = __float_as_uint(v1.y),
                   u6 = __float_as_uint(v1.z), u7 = __float_as_uint(v1.w);
    hi.q.x = __builtin_amdgcn_perm(u1, u0, 0x07060302u);
    hi.q.y = __builtin_amdgcn_perm(u3, u2, 0x07060302u);
    hi.q.z = __builtin_amdgcn_perm(u5, u4, 0x07060302u);
    hi.q.w = __builtin_amdgcn_perm(u7, u6, 0x07060302u);
    const unsigned l0 = __float_as_uint(v0.x - __uint_as_float(u0 & 0xffff0000u));
    const unsigned l1 = __float_as_uint(v0.y - __uint_as_float(u1 & 0xffff0000u));
    const unsigned l2 = __float_as_uint(v0.z - __uint_as_float(u2 & 0xffff0000u));
    const unsigned l3 = __float_as_uint(v0.w - __uint_as_float(u3 & 0xffff0000u));
    const unsigned l4 = __float_as_uint(v1.x - __uint_as_float(u4 & 0xffff0000u));
    const unsigned l5 = __float_as_uint(v1.y - __uint_as_float(u5 & 0xffff0000u));
    const unsigned l6 = __float_as_uint(v1.z - __uint_as_float(u6 & 0xffff0000u));
    const unsigned l7 = __float_as_uint(v1.w - __uint_as_float(u7 & 0xffff0000u));
    lo.q.x = __builtin_amdgcn_perm(l1, l0, 0x07060302u);
    lo.q.y = __builtin_amdgcn_perm(l3, l2, 0x07060302u);
    lo.q.z = __builtin_amdgcn_perm(l5, l4, 0x07060302u);
    lo.q.w = __builtin_amdgcn_perm(l7, l6, 0x07060302u);
}

// ---------------------------------------------------------------------------
// k_prep: fused one-time prep + x-moments (block-range dispatch, 1420 blocks):
//  bx <  384 : frags — bhi/be1/be2 (t<32768) + CwE hi/lo (all t)
//  bx <  396 : k_D — D[kpos][o] via MFMA, logf inline (12 blocks)
//  else      : k_mom — per-chunk weighted moments of x (1024 blocks)
// ---------------------------------------------------------------------------
__global__ __launch_bounds__(256) void k_prep(
    const float* __restrict__ bmat, const float* __restrict__ cmat,
    const float* __restrict__ a, const float* __restrict__ x,
    unsigned short* __restrict__ bhi, unsigned short* __restrict__ be1,
    unsigned short* __restrict__ be2,
    unsigned short* __restrict__ CwEh, unsigned short* __restrict__ CwEl,
    unsigned short* __restrict__ Dstk, unsigned short* __restrict__ Xm)
{
    const int bx = blockIdx.x;
    if (bx < 384) {
        const int t = bx * 256 + threadIdx.x;   // 0..98303
        if (t < 32768) {
            const int j = t & 7, n = (t >> 3) & 15, g = (t >> 7) & 3;
            const int nt = (t >> 9) & 31, kb = (t >> 14) & 1;
            const int h = nt * 16 + n;
            const float v = bmat[(size_t)(kb * 32 + g * 8 + j) * DH_ + h];
            const float u = logf(a[h]);
            bhi[t] = f2b_rne(v);
            be1[t] = f2b_rne(v * u);
            be2[t] = f2b_rne(v * u * u * 0.5f);
        }
        {
            const int j = t & 7;
            const int lane = (t >> 3) & 63;
            const int rem = t >> 9;             // 0..191
            const int nt = rem % 12, kb = rem / 12;
            const int h = kb * 32 + (lane >> 4) * 8 + j;
            const int n = nt * 16 + (lane & 15);
            const int m = n >> 6, o = n & 63;
            const float av = a[h];
            const float u = logf(av);
            const float w = (m == 0) ? av : ((m == 1) ? av * u : av * u * u * 0.5f);
            const float v = w * cmat[(size_t)h * DO_ + o];
            unsigned short hi16 = (unsigned short)(__float_as_uint(v) >> 16);
            float lo = v - __uint_as_float(((unsigned)hi16) << 16);
            CwEh[t] = hi16;
            CwEl[t] = (unsigned short)(__float_as_uint(lo) >> 16);
        }
    } else if (bx < 396) {
        // ---- k_D path: D[kpos][o] = sum_h b[i][h] * w_p[h] * c[h][o] ----
        const int mt   = bx - 384;         // 0..11
        const int tid  = threadIdx.x;
        const int lane = tid & 63;
        const int nt   = tid >> 6;         // 0..3
        const int lm   = lane & 15;
        const int lg   = lane >> 4;

        const int kposr = mt * 16 + lm;
        int p, i;
        if (kposr < 128) { i = kposr >> 1; p = kposr & 1; }
        else             { p = 2; i = kposr - 128; }

        f32x4 acc = {0.f, 0.f, 0.f, 0.f};
#pragma unroll
        for (int kb = 0; kb < 16; ++kb) {
            const int h0 = kb * 32 + lg * 8;
            const float4 b0 = *(const float4*)(bmat + (size_t)i * DH_ + h0);
            const float4 b1 = *(const float4*)(bmat + (size_t)i * DH_ + h0 + 4);
            const float bv[8] = {b0.x, b0.y, b0.z, b0.w, b1.x, b1.y, b1.z, b1.w};
            U8 af, cf;
            bfv8 ab, cb;
#pragma unroll
            for (int j = 0; j < 8; ++j) {
                float wp = 1.f;
                if (p > 0) {
                    const float u = logf(a[h0 + j]);
                    wp = (p == 1) ? u : u * u * 0.5f;
                }
                ab[j] = (__bf16)(bv[j] * wp);
                cb[j] = (__bf16)cmat[(size_t)(h0 + j) * DO_ + nt * 16 + lm];
            }
            af.b = ab; cf.b = cb;
            acc = __builtin_amdgcn_mfma_f32_16x16x32_bf16(af.v, cf.v, acc, 0, 0, 0);
        }
#pragma unroll
        for (int rg = 0; rg < 4; ++rg) {
            const int kpos = mt * 16 + lg * 4 + rg;
            const int o    = nt * 16 + lm;
            Dstk[((size_t)((kpos >> 5) * 4 + (o >> 4)) * 64 + ((kpos >> 3) & 3) * 16 + (o & 15)) * 8 + (kpos & 7)]
                = f2b_rne(acc[rg]);
        }
    } else {
        // ---- k_mom path ----
        const int m   = bx - 396;              // 0..1023
        const int c   = m >> 4;
        const int idx = (m & 15) * 256 + threadIdx.x;
        const float* xp = x + (size_t)c * 64 * 4096 + idx;

        float m0 = 0.f, m1 = 0.f, m2 = 0.f;
#pragma unroll
        for (int s = 0; s < 64; ++s) {
            const float v = xp[(size_t)s * 4096];
            const float t = (float)(63 - s);
            m0 += v;
            m1 = fmaf(t, v, m1);
            m2 = fmaf(t * t, v, m2);
        }
        __bf16* Xb = (__bf16*)Xm;
        Xb[(size_t)(c * 3 + 0) * 4096 + idx] = (__bf16)m0;
        Xb[(size_t)(c * 3 + 1) * 4096 + idx] = (__bf16)m1;
        Xb[(size_t)(c * 3 + 2) * 4096 + idx] = (__bf16)m2;
    }
}

// ---------------------------------------------------------------------------
// k_rg: r[c][bb][h] = sum_k (u^k/k!)(X_k @ b)[h], one GEMM K=192 folded.
// ---------------------------------------------------------------------------
__global__ __launch_bounds__(512) void k_rg(
    const unsigned short* __restrict__ Xm,
    const unsigned short* __restrict__ bhi, const unsigned short* __restrict__ be1,
    const unsigned short* __restrict__ be2,
    float* __restrict__ r)
{
    const int c    = blockIdx.x;
    const int nh   = blockIdx.y;
    const int tid  = threadIdx.x;
    const int lane = tid & 63;
    const int w    = tid >> 6;
    const int lm   = lane & 15;
    const int lg   = lane >> 4;

    bf16x8 af[4][6];
#pragma unroll
    for (int mt = 0; mt < 4; ++mt)
#pragma unroll
        for (int kb = 0; kb < 6; ++kb) {
            const int mom = kb >> 1;
            af[mt][kb] = *(const bf16x8*)(Xm + (size_t)(c * 3 + mom) * 4096
                                          + (mt * 16 + lm) * 64 + (kb & 1) * 32 + lg * 8);
        }

    bf16x8 bfr[6][2];
#pragma unroll
    for (int kb = 0; kb < 6; ++kb) {
        const int mom = kb >> 1;
        const unsigned short* base = (mom == 0) ? bhi : (mom == 1) ? be1 : be2;
#pragma unroll
        for (int nt = 0; nt < 2; ++nt) {
            const int ntg = nh * 16 + w * 2 + nt;
            bfr[kb][nt] = *(const bf16x8*)(base + ((size_t)((kb & 1) * 32 + ntg) * 64 + lane) * 8);
        }
    }

    f32x4 acc[4][2];
#pragma unroll
    for (int mt = 0; mt < 4; ++mt)
#pragma unroll
        for (int nt = 0; nt < 2; ++nt) acc[mt][nt] = (f32x4){0.f, 0.f, 0.f, 0.f};

#pragma unroll
    for (int kb = 0; kb < 6; ++kb)
#pragma unroll
        for (int nt = 0; nt < 2; ++nt)
#pragma unroll
            for (int mt = 0; mt < 4; ++mt)
                acc[mt][nt] = __builtin_amdgcn_mfma_f32_16x16x32_bf16(af[mt][kb], bfr[kb][nt], acc[mt][nt], 0, 0, 0);

#pragma unroll
    for (int mt = 0; mt < 4; ++mt)
#pragma unroll
        for (int nt = 0; nt < 2; ++nt)
#pragma unroll
            for (int rg = 0; rg < 4; ++rg) {
                const int bb = mt * 16 + lg * 4 + rg;
                const int h  = nh * 256 + w * 32 + nt * 16 + lm;
                r[((size_t)c * B_ + bb) * DH_ + h] = acc[mt][nt][rg];
            }
}

// ---------------------------------------------------------------------------
// k_scan: sequential scan over chunk aggregates, IN PLACE (r becomes Hst).
// ---------------------------------------------------------------------------
__global__ __launch_bounds__(512) void k_scan(
    const float* __restrict__ h0, const float* __restrict__ a,
    float* __restrict__ r, float* __restrict__ hfin)
{
    const int bb  = blockIdx.x;
    const int hid = threadIdx.x;
    const size_t base = (size_t)bb * DH_ + hid;

    float rv[C_];
#pragma unroll
    for (int c = 0; c < C_; ++c) rv[c] = r[(size_t)c * B_ * DH_ + base];

    float h  = h0[base];
    float aL = a[hid];
#pragma unroll
    for (int q = 0; q < 6; ++q) aL = aL * aL;   // a^64

#pragma unroll
    for (int c = 0; c < C_; ++c) {
        r[(size_t)c * B_ * DH_ + base] = h;      // Hst[c]
        h = fmaf(h, aL, rv[c]);
    }
    hfin[base] = h;
}

// ---------------------------------------------------------------------------
// k_E: E[(c*64+bb)][n] = Hst row @ CwE (M=4096, N=192, K=512), hi/lo 3-term.
// grid (4*C_, 3) x 256 threads.
// ---------------------------------------------------------------------------
__global__ __launch_bounds__(256) void k_E(
    const float* __restrict__ Hst,
    const unsigned short* __restrict__ CwEh, const unsigned short* __restrict__ CwEl,
    float* __restrict__ E)
{
    const int bx   = blockIdx.x;
    const int c    = bx >> 2;
    const int ms   = bx & 3;
    const int nb   = blockIdx.y;
    const int tid  = threadIdx.x;
    const int lane = tid & 63;
    const int w    = tid >> 6;
    const int lm   = lane & 15;
    const int lg   = lane >> 4;

    f32x4 acc = {0.f, 0.f, 0.f, 0.f};
    const int ntg = nb * 4 + w;

    for (int kb = 0; kb < 16; ++kb) {
        const float* ap = Hst + (size_t)(c * 64 + ms * 16 + lm) * DH_ + kb * 32 + lg * 8;
        U8 ahi, alo;
        trunc_split8(*(const float4*)ap, *(const float4*)(ap + 4), ahi, alo);
        const size_t fo = ((size_t)(kb * 12 + ntg) * 64 + lane) * 8;
        const bf16x8 bh = *(const bf16x8*)(CwEh + fo);
        const bf16x8 bl = *(const bf16x8*)(CwEl + fo);
        acc = __builtin_amdgcn_mfma_f32_16x16x32_bf16(ahi.v, bh, acc, 0, 0, 0);
        acc = __builtin_amdgcn_mfma_f32_16x16x32_bf16(alo.v, bh, acc, 0, 0, 0);
        acc = __builtin_amdgcn_mfma_f32_16x16x32_bf16(ahi.v, bl, acc, 0, 0, 0);
    }

#pragma unroll
    for (int rg = 0; rg < 4; ++rg) {
        const int row = ms * 16 + lg * 4 + rg;
        E[(size_t)(c * 64 + row) * 192 + ntg * 16 + lm] = acc[rg];
    }
}

// ---------------------------------------------------------------------------
// k_y: per (chunk, batch) block, 512 threads, LDS 30720 B -> 4 blk/CU.
//  ph2 (PARALLEL two-level prefix scan): thread (i = col, j = wave) loads its
//    8 x-values (all 512 threads pull x in parallel), computes segment moment
//    partials L0/L1/L2 -> LDS prefix buffer; barrier; offsets by sum_{k<j} L;
//    8 serial steps emit A0/A1/A2 into the swizzled A-tile.
//  ph3: y = A @ Dstk (K=192) + E epilogue. Unchanged.
// ---------------------------------------------------------------------------
__global__ __launch_bounds__(512, 8) void k_y(
    const float* __restrict__ x,
    const unsigned short* __restrict__ Dstk,
    const float* __restrict__ E,
    float* __restrict__ y)
{
    __shared__ __align__(16) unsigned short At[64 * 192];  // 24576 B
    __shared__ float Lb[3][8][64];                          // 6144 B

    const int c    = blockIdx.x;
    const int bb   = blockIdx.y;
    const int tid  = threadIdx.x;
    const int lane = tid & 63;
    const int w    = tid >> 6;
    const int lm   = lane & 15;
    const int lg   = lane >> 4;
    const int mp   = w >> 2;
    const int oq   = w & 3;
    const int o    = oq * 16 + lm;

    // ---- ph2: parallel prefix-moment scan ----
    {
        const int i = tid & 63;   // column
        const int j = w;          // 8-step segment

        const float* xp = x + (((size_t)(c * 64 + j * 8)) * 64 + bb) * 64 + i;
        float v[8];
#pragma unroll
        for (int t = 0; t < 8; ++t) v[t] = xp[(size_t)t * 4096];

        float L0 = 0.f, L1 = 0.f, L2 = 0.f;
#pragma unroll
        for (int t = 0; t < 8; ++t) {
            const float sf = (float)(j * 8 + t);
            L0 += v[t];
            L1 = fmaf(sf, v[t], L1);
            L2 = fmaf(sf * sf, v[t], L2);
        }
        Lb[0][j][i] = L0; Lb[1][j][i] = L1; Lb[2][j][i] = L2;
        __syncthreads();

        float S0 = 0.f, S1 = 0.f, S2 = 0.f;
        for (int k = 0; k < j; ++k) {   // j is wave-uniform: no divergence
            S0 += Lb[0][k][i];
            S1 += Lb[1][k][i];
            S2 += Lb[2][k][i];
        }

        char* Ab = (char*)At;
#pragma unroll
        for (int t = 0; t < 8; ++t) {
            const int s = j * 8 + t;
            const float sf = (float)s;
            S0 += v[t];
            S1 = fmaf(sf, v[t], S1);
            S2 = fmaf(sf * sf, v[t], S2);
            const float A0 = S0;
            const float A1 = fmaf(sf, S0, -S1);
            const float A2 = fmaf(sf, fmaf(sf, S0, -2.0f * S1), S2);
            const int f = t << 4;   // (s & 7) == t
            U2 pk; pk.b = __builtin_convertvector((f32x2){A0, A1}, bfv2);
            *(unsigned*)(Ab + ((s * 384 + 4 * i) ^ f)) = pk.u;
            *(__bf16*)(Ab + ((s * 384 + 256 + 2 * i) ^ f)) = (__bf16)A2;
        }
    }
    __syncthreads();

    // E-term loads: latency hides under ph3 MFMAs
    const size_t erow = (size_t)(c * 64 + bb) * 192;
    const float e0 = E[erow + o];
    const float e1 = E[erow + 64 + o];
    const float e2 = E[erow + 128 + o];

    // ---- ph3: y = A @ D + E-term ----
    {
        const int row0 = (mp * 2 + 0) * 16 + lm;
        const int row1 = (mp * 2 + 1) * 16 + lm;
        const int f0 = (row0 & 7) << 4;
        const int f1 = (row1 & 7) << 4;
        const char* Ab = (const char*)At;

        f32x4 acc0 = {0.f, 0.f, 0.f, 0.f};
        f32x4 acc1 = {0.f, 0.f, 0.f, 0.f};

        __builtin_amdgcn_s_setprio(1);
#pragma unroll
        for (int kb = 0; kb < 6; ++kb) {
            const int b2k = kb * 64 + lg * 16;
            const bf16x8 a0 = *(const bf16x8*)(Ab + ((row0 * 384 + b2k) ^ f0));
            const bf16x8 a1 = *(const bf16x8*)(Ab + ((row1 * 384 + b2k) ^ f1));
            const bf16x8 df = *(const bf16x8*)(Dstk + ((size_t)(kb * 4 + oq) * 64 + lane) * 8);
            acc0 = __builtin_amdgcn_mfma_f32_16x16x32_bf16(a0, df, acc0, 0, 0, 0);
            acc1 = __builtin_amdgcn_mfma_f32_16x16x32_bf16(a1, df, acc1, 0, 0, 0);
        }
        __builtin_amdgcn_s_setprio(0);

#pragma unroll
        for (int rg = 0; rg < 4; ++rg) {
            const int sr0 = (mp * 2 + 0) * 16 + lg * 4 + rg;
            const int sr1 = (mp * 2 + 1) * 16 + lg * 4 + rg;
            const float s0f = (float)sr0, s1f = (float)sr1;
            const float y0 = acc0[rg] + fmaf(s0f, fmaf(s0f, e2, e1), e0);
            const float y1 = acc1[rg] + fmaf(s1f, fmaf(s1f, e2, e1), e0);
            y[(((size_t)(c * 64 + sr0)) * 64 + bb) * 64 + o] = y0;
            y[(((size_t)(c * 64 + sr1)) * 64 + bb) * 64 + o] = y1;
        }
    }
}

// ---------------------------------------------------------------------------
extern "C" void kernel_launch(void* const* d_in, const int* in_sizes, int n_in,
                              void* d_out, int out_size, void* d_ws, size_t ws_size,
                              hipStream_t stream) {
    (void)in_sizes; (void)n_in; (void)out_size; (void)ws_size;

    const float* h0 = (const float*)d_in[0];   // [B, DH]
    const float* x  = (const float*)d_in[1];   // [T, B, DI]
    const float* a  = (const float*)d_in[2];   // [DH]
    const float* bm = (const float*)d_in[3];   // [DI, DH]
    const float* cm = (const float*)d_in[4];   // [DH, DO]

    float* out  = (float*)d_out;
    float* hfin = out;                         // [B, DH]
    float* y    = out + (size_t)B_ * DH_;      // [T, B, DO]

    float* r = (float*)d_ws;                   // [C,B,DH] f32 (8 MB), becomes Hst
    unsigned short* bhi  = (unsigned short*)(r + (size_t)C_ * B_ * DH_);
    unsigned short* be1  = bhi + 32768;
    unsigned short* be2  = be1 + 32768;
    unsigned short* CwEh = be2 + 32768;        // 98304
    unsigned short* CwEl = CwEh + 98304;       // 98304
    unsigned short* Dstk = CwEl + 98304;       // 12288
    unsigned short* Xm   = Dstk + 12288;       // [C][3][4096] bf16
    float* E = (float*)(Xm + (size_t)C_ * 3 * 4096);   // [4096][192] f32

    k_prep<<<dim3(1420), 256, 0, stream>>>(bm, cm, a, x, bhi, be1, be2, CwEh, CwEl, Dstk, Xm);
    k_rg<<<dim3(C_, 2), 512, 0, stream>>>(Xm, bhi, be1, be2, r);
    k_scan<<<dim3(B_), 512, 0, stream>>>(h0, a, r, hfin);
    k_E<<<dim3(4 * C_, 3), 256, 0, stream>>>(r, CwEh, CwEl, E);
    k_y<<<dim3(C_, B_), 512, 0, stream>>>(x, Dstk, E, y);
}

// Round 18
// 100.451 us; speedup vs baseline: 1.2358x; 1.2358x over previous
//
#include <hip/hip_runtime.h>
#include <stdint.h>

// Problem constants
#define T_  4096
#define B_  64
#define DI_ 64
#define DH_ 512
#define DO_ 64
#define L_  64          // chunk length
#define C_  (T_ / L_)   // 64 chunks

typedef __attribute__((ext_vector_type(8))) short bf16x8;
typedef __attribute__((ext_vector_type(2))) float f32x2;
typedef __attribute__((ext_vector_type(4))) float f32x4;
typedef __attribute__((ext_vector_type(8))) float f32x8;
typedef __attribute__((ext_vector_type(2))) __bf16 bfv2;
typedef __attribute__((ext_vector_type(8))) __bf16 bfv8;

union U8 { uint4 q; bf16x8 v; bfv8 b; };
union U2 { unsigned u; bfv2 b; };

__device__ inline unsigned short f2b_rne(float f) {
    unsigned u = __float_as_uint(f);
    return (unsigned short)((u + 0x7fffu + ((u >> 16) & 1u)) >> 16);
}

// trunc-split 8 f32 -> hi bf16x8 + lo bf16x8 (combined rel err ~2^-16)
__device__ inline void trunc_split8(const float4 v0, const float4 v1, U8& hi, U8& lo) {
    const unsigned u0 = __float_as_uint(v0.x), u1 = __float_as_uint(v0.y),
                   u2 = __float_as_uint(v0.z), u3 = __float_as_uint(v0.w),
                   u4 = __float_as_uint(v1.x), u5 = __float_as_uint(v1.y),
                   u6 = __float_as_uint(v1.z), u7 = __float_as_uint(v1.w);
    hi.q.x = __builtin_amdgcn_perm(u1, u0, 0x07060302u);
    hi.q.y = __builtin_amdgcn_perm(u3, u2, 0x07060302u);
    hi.q.z = __builtin_amdgcn_perm(u5, u4, 0x07060302u);
    hi.q.w = __builtin_amdgcn_perm(u7, u6, 0x07060302u);
    const unsigned l0 = __float_as_uint(v0.x - __uint_as_float(u0 & 0xffff0000u));
    const unsigned l1 = __float_as_uint(v0.y - __uint_as_float(u1 & 0xffff0000u));
    const unsigned l2 = __float_as_uint(v0.z - __uint_as_float(u2 & 0xffff0000u));
    const unsigned l3 = __float_as_uint(v0.w - __uint_as_float(u3 & 0xffff0000u));
    const unsigned l4 = __float_as_uint(v1.x - __uint_as_float(u4 & 0xffff0000u));
    const unsigned l5 = __float_as_uint(v1.y - __uint_as_float(u5 & 0xffff0000u));
    const unsigned l6 = __float_as_uint(v1.z - __uint_as_float(u6 & 0xffff0000u));
    const unsigned l7 = __float_as_uint(v1.w - __uint_as_float(u7 & 0xffff0000u));
    lo.q.x = __builtin_amdgcn_perm(l1, l0, 0x07060302u);
    lo.q.y = __builtin_amdgcn_perm(l3, l2, 0x07060302u);
    lo.q.z = __builtin_amdgcn_perm(l5, l4, 0x07060302u);
    lo.q.w = __builtin_amdgcn_perm(l7, l6, 0x07060302u);
}

// ---------------------------------------------------------------------------
// k_frags: (A) bhi/be1/be2 frags for k_rg; (B) CwE hi/lo frags for k_E;
// (C) u_arr[h] = logf(a[h]) for k_D. grid 384 x 256.
// ---------------------------------------------------------------------------
__global__ __launch_bounds__(256) void k_frags(
    const float* __restrict__ bmat, const float* __restrict__ cmat,
    const float* __restrict__ a,
    unsigned short* __restrict__ bhi, unsigned short* __restrict__ be1,
    unsigned short* __restrict__ be2,
    unsigned short* __restrict__ CwEh, unsigned short* __restrict__ CwEl,
    float* __restrict__ u_arr)
{
    const int t = blockIdx.x * 256 + threadIdx.x;   // 0..98303
    if (t < 512) u_arr[t] = logf(a[t]);
    if (t < 32768) {
        const int j = t & 7, n = (t >> 3) & 15, g = (t >> 7) & 3;
        const int nt = (t >> 9) & 31, kb = (t >> 14) & 1;
        const int h = nt * 16 + n;
        const float v = bmat[(size_t)(kb * 32 + g * 8 + j) * DH_ + h];
        const float u = logf(a[h]);
        bhi[t] = f2b_rne(v);
        be1[t] = f2b_rne(v * u);
        be2[t] = f2b_rne(v * u * u * 0.5f);
    }
    {
        const int j = t & 7;
        const int lane = (t >> 3) & 63;
        const int rem = t >> 9;             // 0..191
        const int nt = rem % 12, kb = rem / 12;
        const int h = kb * 32 + (lane >> 4) * 8 + j;
        const int n = nt * 16 + (lane & 15);
        const int m = n >> 6, o = n & 63;
        const float av = a[h];
        const float u = logf(av);
        const float w = (m == 0) ? av : ((m == 1) ? av * u : av * u * u * 0.5f);
        const float v = w * cmat[(size_t)h * DO_ + o];
        unsigned short hi16 = (unsigned short)(__float_as_uint(v) >> 16);
        float lo = v - __uint_as_float(((unsigned)hi16) << 16);
        CwEh[t] = hi16;
        CwEl[t] = (unsigned short)(__float_as_uint(lo) >> 16);
    }
}

// ---------------------------------------------------------------------------
// k_D (MFMA): D[kpos][o] = sum_h b[i(kpos)][h] * w_p(kpos)[h] * c[h][o].
// grid 12 x 256, output in Dstk B-frag layout (bf16).
// ---------------------------------------------------------------------------
__global__ __launch_bounds__(256) void k_D(
    const float* __restrict__ bmat, const float* __restrict__ cmat,
    const float* __restrict__ u_arr, unsigned short* __restrict__ Dstk)
{
    const int mt   = blockIdx.x;       // 0..11
    const int tid  = threadIdx.x;
    const int lane = tid & 63;
    const int nt   = tid >> 6;         // 0..3
    const int lm   = lane & 15;
    const int lg   = lane >> 4;

    const int kposr = mt * 16 + lm;
    int p, i;
    if (kposr < 128) { i = kposr >> 1; p = kposr & 1; }
    else             { p = 2; i = kposr - 128; }

    f32x4 acc = {0.f, 0.f, 0.f, 0.f};
#pragma unroll
    for (int kb = 0; kb < 16; ++kb) {
        const int h0 = kb * 32 + lg * 8;
        const float4 b0 = *(const float4*)(bmat + (size_t)i * DH_ + h0);
        const float4 b1 = *(const float4*)(bmat + (size_t)i * DH_ + h0 + 4);
        const float4 w0 = *(const float4*)(u_arr + h0);
        const float4 w1 = *(const float4*)(u_arr + h0 + 4);
        const float bv[8] = {b0.x, b0.y, b0.z, b0.w, b1.x, b1.y, b1.z, b1.w};
        const float uv[8] = {w0.x, w0.y, w0.z, w0.w, w1.x, w1.y, w1.z, w1.w};
        U8 af, cf;
        bfv8 ab, cb;
#pragma unroll
        for (int j = 0; j < 8; ++j) {
            const float wp = (p == 0) ? 1.f : ((p == 1) ? uv[j] : uv[j] * uv[j] * 0.5f);
            ab[j] = (__bf16)(bv[j] * wp);
            cb[j] = (__bf16)cmat[(size_t)(h0 + j) * DO_ + nt * 16 + lm];
        }
        af.b = ab; cf.b = cb;
        acc = __builtin_amdgcn_mfma_f32_16x16x32_bf16(af.v, cf.v, acc, 0, 0, 0);
    }

#pragma unroll
    for (int rg = 0; rg < 4; ++rg) {
        const int kpos = mt * 16 + lg * 4 + rg;
        const int o    = nt * 16 + lm;
        Dstk[((size_t)((kpos >> 5) * 4 + (o >> 4)) * 64 + ((kpos >> 3) & 3) * 16 + (o & 15)) * 8 + (kpos & 7)]
            = f2b_rne(acc[rg]);
    }
}

// ---------------------------------------------------------------------------
// k_mom: per-chunk moment reduction over x (streaming). R14-identical.
// ---------------------------------------------------------------------------
__global__ __launch_bounds__(256) void k_mom(
    const float* __restrict__ x, unsigned short* __restrict__ Xm)
{
    const int c   = blockIdx.x;
    const int idx = blockIdx.y * 256 + threadIdx.x;
    const float* xp = x + (size_t)c * 64 * 4096 + idx;

    float m0 = 0.f, m1 = 0.f, m2 = 0.f;
#pragma unroll
    for (int s = 0; s < 64; ++s) {
        const float v = xp[(size_t)s * 4096];
        const float t = (float)(63 - s);
        m0 += v;
        m1 = fmaf(t, v, m1);
        m2 = fmaf(t * t, v, m2);
    }
    __bf16* Xb = (__bf16*)Xm;
    Xb[(size_t)(c * 3 + 0) * 4096 + idx] = (__bf16)m0;
    Xb[(size_t)(c * 3 + 1) * 4096 + idx] = (__bf16)m1;
    Xb[(size_t)(c * 3 + 2) * 4096 + idx] = (__bf16)m2;
}

// ---------------------------------------------------------------------------
// k_rg: r[c][bb][h] = sum_k (u^k/k!)(X_k @ b)[h], one GEMM K=192 folded.
// ---------------------------------------------------------------------------
__global__ __launch_bounds__(512) void k_rg(
    const unsigned short* __restrict__ Xm,
    const unsigned short* __restrict__ bhi, const unsigned short* __restrict__ be1,
    const unsigned short* __restrict__ be2,
    float* __restrict__ r)
{
    const int c    = blockIdx.x;
    const int nh   = blockIdx.y;
    const int tid  = threadIdx.x;
    const int lane = tid & 63;
    const int w    = tid >> 6;
    const int lm   = lane & 15;
    const int lg   = lane >> 4;

    bf16x8 af[4][6];
#pragma unroll
    for (int mt = 0; mt < 4; ++mt)
#pragma unroll
        for (int kb = 0; kb < 6; ++kb) {
            const int mom = kb >> 1;
            af[mt][kb] = *(const bf16x8*)(Xm + (size_t)(c * 3 + mom) * 4096
                                          + (mt * 16 + lm) * 64 + (kb & 1) * 32 + lg * 8);
        }

    bf16x8 bfr[6][2];
#pragma unroll
    for (int kb = 0; kb < 6; ++kb) {
        const int mom = kb >> 1;
        const unsigned short* base = (mom == 0) ? bhi : (mom == 1) ? be1 : be2;
#pragma unroll
        for (int nt = 0; nt < 2; ++nt) {
            const int ntg = nh * 16 + w * 2 + nt;
            bfr[kb][nt] = *(const bf16x8*)(base + ((size_t)((kb & 1) * 32 + ntg) * 64 + lane) * 8);
        }
    }

    f32x4 acc[4][2];
#pragma unroll
    for (int mt = 0; mt < 4; ++mt)
#pragma unroll
        for (int nt = 0; nt < 2; ++nt) acc[mt][nt] = (f32x4){0.f, 0.f, 0.f, 0.f};

#pragma unroll
    for (int kb = 0; kb < 6; ++kb)
#pragma unroll
        for (int nt = 0; nt < 2; ++nt)
#pragma unroll
            for (int mt = 0; mt < 4; ++mt)
                acc[mt][nt] = __builtin_amdgcn_mfma_f32_16x16x32_bf16(af[mt][kb], bfr[kb][nt], acc[mt][nt], 0, 0, 0);

#pragma unroll
    for (int mt = 0; mt < 4; ++mt)
#pragma unroll
        for (int nt = 0; nt < 2; ++nt)
#pragma unroll
            for (int rg = 0; rg < 4; ++rg) {
                const int bb = mt * 16 + lg * 4 + rg;
                const int h  = nh * 256 + w * 32 + nt * 16 + lm;
                r[((size_t)c * B_ + bb) * DH_ + h] = acc[mt][nt][rg];
            }
}

// ---------------------------------------------------------------------------
// k_scan: sequential scan over chunk aggregates, IN PLACE (r becomes Hst).
// ---------------------------------------------------------------------------
__global__ __launch_bounds__(512) void k_scan(
    const float* __restrict__ h0, const float* __restrict__ a,
    float* __restrict__ r, float* __restrict__ hfin)
{
    const int bb  = blockIdx.x;
    const int hid = threadIdx.x;
    const size_t base = (size_t)bb * DH_ + hid;

    float rv[C_];
#pragma unroll
    for (int c = 0; c < C_; ++c) rv[c] = r[(size_t)c * B_ * DH_ + base];

    float h  = h0[base];
    float aL = a[hid];
#pragma unroll
    for (int q = 0; q < 6; ++q) aL = aL * aL;   // a^64

#pragma unroll
    for (int c = 0; c < C_; ++c) {
        r[(size_t)c * B_ * DH_ + base] = h;      // Hst[c]
        h = fmaf(h, aL, rv[c]);
    }
    hfin[base] = h;
}

// ---------------------------------------------------------------------------
// k_E: E[(c*64+bb)][n] = Hst row @ CwE (M=4096, N=192, K=512), hi/lo 3-term.
// Re-gridded: grid (4*C_, 3) x 256 threads (768 blocks, 3/CU).
// ---------------------------------------------------------------------------
__global__ __launch_bounds__(256) void k_E(
    const float* __restrict__ Hst,
    const unsigned short* __restrict__ CwEh, const unsigned short* __restrict__ CwEl,
    float* __restrict__ E)
{
    const int bx   = blockIdx.x;
    const int c    = bx >> 2;
    const int ms   = bx & 3;
    const int nb   = blockIdx.y;
    const int tid  = threadIdx.x;
    const int lane = tid & 63;
    const int w    = tid >> 6;
    const int lm   = lane & 15;
    const int lg   = lane >> 4;

    f32x4 acc = {0.f, 0.f, 0.f, 0.f};
    const int ntg = nb * 4 + w;

    for (int kb = 0; kb < 16; ++kb) {
        const float* ap = Hst + (size_t)(c * 64 + ms * 16 + lm) * DH_ + kb * 32 + lg * 8;
        U8 ahi, alo;
        trunc_split8(*(const float4*)ap, *(const float4*)(ap + 4), ahi, alo);
        const size_t fo = ((size_t)(kb * 12 + ntg) * 64 + lane) * 8;
        const bf16x8 bh = *(const bf16x8*)(CwEh + fo);
        const bf16x8 bl = *(const bf16x8*)(CwEl + fo);
        acc = __builtin_amdgcn_mfma_f32_16x16x32_bf16(ahi.v, bh, acc, 0, 0, 0);
        acc = __builtin_amdgcn_mfma_f32_16x16x32_bf16(alo.v, bh, acc, 0, 0, 0);
        acc = __builtin_amdgcn_mfma_f32_16x16x32_bf16(ahi.v, bl, acc, 0, 0, 0);
    }

#pragma unroll
    for (int rg = 0; rg < 4; ++rg) {
        const int row = ms * 16 + lg * 4 + rg;
        E[(size_t)(c * 64 + row) * 192 + ntg * 16 + lm] = acc[rg];
    }
}

// ---------------------------------------------------------------------------
// k_y: per (chunk, batch) block, 512 threads, LDS 30720 B, (512,6) -> 3 blk/CU.
//  ph2 (parallel two-level prefix scan, verified R16): thread (i=col, j=wave)
//    loads its 8 x-values (512 threads pull x in parallel), computes segment
//    partials -> LDS; barrier; offset by prefix of partials; 8 serial steps
//    emit A0/A1/A2 into the swizzled A-tile.
//  ph3: y = A @ Dstk (K=192) + E epilogue.
// ---------------------------------------------------------------------------
__global__ __launch_bounds__(512, 6) void k_y(
    const float* __restrict__ x,
    const unsigned short* __restrict__ Dstk,
    const float* __restrict__ E,
    float* __restrict__ y)
{
    __shared__ __align__(16) unsigned short At[64 * 192];  // 24576 B
    __shared__ float Lb[3][8][64];                          // 6144 B

    const int c    = blockIdx.x;
    const int bb   = blockIdx.y;
    const int tid  = threadIdx.x;
    const int lane = tid & 63;
    const int w    = tid >> 6;
    const int lm   = lane & 15;
    const int lg   = lane >> 4;
    const int mp   = w >> 2;
    const int oq   = w & 3;
    const int o    = oq * 16 + lm;

    // ---- ph2: parallel prefix-moment scan ----
    {
        const int i = tid & 63;   // column
        const int j = w;          // 8-step segment

        const float* xp = x + (((size_t)(c * 64 + j * 8)) * 64 + bb) * 64 + i;
        float v[8];
#pragma unroll
        for (int t = 0; t < 8; ++t) v[t] = xp[(size_t)t * 4096];

        float L0 = 0.f, L1 = 0.f, L2 = 0.f;
#pragma unroll
        for (int t = 0; t < 8; ++t) {
            const float sf = (float)(j * 8 + t);
            L0 += v[t];
            L1 = fmaf(sf, v[t], L1);
            L2 = fmaf(sf * sf, v[t], L2);
        }
        Lb[0][j][i] = L0; Lb[1][j][i] = L1; Lb[2][j][i] = L2;
        __syncthreads();

        float S0 = 0.f, S1 = 0.f, S2 = 0.f;
        for (int k = 0; k < j; ++k) {   // j is wave-uniform: no divergence
            S0 += Lb[0][k][i];
            S1 += Lb[1][k][i];
            S2 += Lb[2][k][i];
        }

        char* Ab = (char*)At;
#pragma unroll
        for (int t = 0; t < 8; ++t) {
            const int s = j * 8 + t;
            const float sf = (float)s;
            S0 += v[t];
            S1 = fmaf(sf, v[t], S1);
            S2 = fmaf(sf * sf, v[t], S2);
            const float A0 = S0;
            const float A1 = fmaf(sf, S0, -S1);
            const float A2 = fmaf(sf, fmaf(sf, S0, -2.0f * S1), S2);
            const int f = t << 4;   // (s & 7) == t
            U2 pk; pk.b = __builtin_convertvector((f32x2){A0, A1}, bfv2);
            *(unsigned*)(Ab + ((s * 384 + 4 * i) ^ f)) = pk.u;
            *(__bf16*)(Ab + ((s * 384 + 256 + 2 * i) ^ f)) = (__bf16)A2;
        }
    }
    __syncthreads();

    // E-term loads: latency hides under ph3 MFMAs
    const size_t erow = (size_t)(c * 64 + bb) * 192;
    const float e0 = E[erow + o];
    const float e1 = E[erow + 64 + o];
    const float e2 = E[erow + 128 + o];

    // ---- ph3: y = A @ D + E-term ----
    {
        const int row0 = (mp * 2 + 0) * 16 + lm;
        const int row1 = (mp * 2 + 1) * 16 + lm;
        const int f0 = (row0 & 7) << 4;
        const int f1 = (row1 & 7) << 4;
        const char* Ab = (const char*)At;

        f32x4 acc0 = {0.f, 0.f, 0.f, 0.f};
        f32x4 acc1 = {0.f, 0.f, 0.f, 0.f};

        __builtin_amdgcn_s_setprio(1);
#pragma unroll
        for (int kb = 0; kb < 6; ++kb) {
            const int b2k = kb * 64 + lg * 16;
            const bf16x8 a0 = *(const bf16x8*)(Ab + ((row0 * 384 + b2k) ^ f0));
            const bf16x8 a1 = *(const bf16x8*)(Ab + ((row1 * 384 + b2k) ^ f1));
            const bf16x8 df = *(const bf16x8*)(Dstk + ((size_t)(kb * 4 + oq) * 64 + lane) * 8);
            acc0 = __builtin_amdgcn_mfma_f32_16x16x32_bf16(a0, df, acc0, 0, 0, 0);
            acc1 = __builtin_amdgcn_mfma_f32_16x16x32_bf16(a1, df, acc1, 0, 0, 0);
        }
        __builtin_amdgcn_s_setprio(0);

#pragma unroll
        for (int rg = 0; rg < 4; ++rg) {
            const int sr0 = (mp * 2 + 0) * 16 + lg * 4 + rg;
            const int sr1 = (mp * 2 + 1) * 16 + lg * 4 + rg;
            const float s0f = (float)sr0, s1f = (float)sr1;
            const float y0 = acc0[rg] + fmaf(s0f, fmaf(s0f, e2, e1), e0);
            const float y1 = acc1[rg] + fmaf(s1f, fmaf(s1f, e2, e1), e0);
            y[(((size_t)(c * 64 + sr0)) * 64 + bb) * 64 + o] = y0;
            y[(((size_t)(c * 64 + sr1)) * 64 + bb) * 64 + o] = y1;
        }
    }
}

// ---------------------------------------------------------------------------
extern "C" void kernel_launch(void* const* d_in, const int* in_sizes, int n_in,
                              void* d_out, int out_size, void* d_ws, size_t ws_size,
                              hipStream_t stream) {
    (void)in_sizes; (void)n_in; (void)out_size; (void)ws_size;

    const float* h0 = (const float*)d_in[0];   // [B, DH]
    const float* x  = (const float*)d_in[1];   // [T, B, DI]
    const float* a  = (const float*)d_in[2];   // [DH]
    const float* bm = (const float*)d_in[3];   // [DI, DH]
    const float* cm = (const float*)d_in[4];   // [DH, DO]

    float* out  = (float*)d_out;
    float* hfin = out;                         // [B, DH]
    float* y    = out + (size_t)B_ * DH_;      // [T, B, DO]

    float* r = (float*)d_ws;                   // [C,B,DH] f32 (8 MB), becomes Hst
    unsigned short* bhi  = (unsigned short*)(r + (size_t)C_ * B_ * DH_);
    unsigned short* be1  = bhi + 32768;
    unsigned short* be2  = be1 + 32768;
    unsigned short* CwEh = be2 + 32768;        // 98304
    unsigned short* CwEl = CwEh + 98304;       // 98304
    unsigned short* Dstk = CwEl + 98304;       // 12288
    unsigned short* Xm   = Dstk + 12288;       // [C][3][4096] bf16
    float* E = (float*)(Xm + (size_t)C_ * 3 * 4096);   // [4096][192] f32
    float* u_arr = E + (size_t)4096 * 192;             // [512] f32

    k_frags<<<dim3(384), 256, 0, stream>>>(bm, cm, a, bhi, be1, be2, CwEh, CwEl, u_arr);
    k_D<<<dim3(12), 256, 0, stream>>>(bm, cm, u_arr, Dstk);
    k_mom<<<dim3(C_, 16), 256, 0, stream>>>(x, Xm);
    k_rg<<<dim3(C_, 2), 512, 0, stream>>>(Xm, bhi, be1, be2, r);
    k_scan<<<dim3(B_), 512, 0, stream>>>(h0, a, r, hfin);
    k_E<<<dim3(4 * C_, 3), 256, 0, stream>>>(r, CwEh, CwEl, E);
    k_y<<<dim3(C_, B_), 512, 0, stream>>>(x, Dstk, E, y);
}

// Round 19
// 95.235 us; speedup vs baseline: 1.3035x; 1.0548x over previous
//
#include <hip/hip_runtime.h>
#include <stdint.h>

// Problem constants
#define T_  4096
#define B_  64
#define DI_ 64
#define DH_ 512
#define DO_ 64
#define L_  64          // chunk length
#define C_  (T_ / L_)   // 64 chunks

typedef __attribute__((ext_vector_type(8))) short bf16x8;
typedef __attribute__((ext_vector_type(2))) float f32x2;
typedef __attribute__((ext_vector_type(4))) float f32x4;
typedef __attribute__((ext_vector_type(8))) float f32x8;
typedef __attribute__((ext_vector_type(2))) __bf16 bfv2;
typedef __attribute__((ext_vector_type(8))) __bf16 bfv8;

union U8 { uint4 q; bf16x8 v; bfv8 b; };
union U2 { unsigned u; bfv2 b; };

__device__ inline unsigned short f2b_rne(float f) {
    unsigned u = __float_as_uint(f);
    return (unsigned short)((u + 0x7fffu + ((u >> 16) & 1u)) >> 16);
}

// trunc-split 8 f32 -> hi bf16x8 + lo bf16x8 (combined rel err ~2^-16)
__device__ inline void trunc_split8(const float4 v0, const float4 v1, U8& hi, U8& lo) {
    const unsigned u0 = __float_as_uint(v0.x), u1 = __float_as_uint(v0.y),
                   u2 = __float_as_uint(v0.z), u3 = __float_as_uint(v0.w),
                   u4 = __float_as_uint(v1.x), u5 = __float_as_uint(v1.y),
                   u6 = __float_as_uint(v1.z), u7 = __float_as_uint(v1.w);
    hi.q.x = __builtin_amdgcn_perm(u1, u0, 0x07060302u);
    hi.q.y = __builtin_amdgcn_perm(u3, u2, 0x07060302u);
    hi.q.z = __builtin_amdgcn_perm(u5, u4, 0x07060302u);
    hi.q.w = __builtin_amdgcn_perm(u7, u6, 0x07060302u);
    const unsigned l0 = __float_as_uint(v0.x - __uint_as_float(u0 & 0xffff0000u));
    const unsigned l1 = __float_as_uint(v0.y - __uint_as_float(u1 & 0xffff0000u));
    const unsigned l2 = __float_as_uint(v0.z - __uint_as_float(u2 & 0xffff0000u));
    const unsigned l3 = __float_as_uint(v0.w - __uint_as_float(u3 & 0xffff0000u));
    const unsigned l4 = __float_as_uint(v1.x - __uint_as_float(u4 & 0xffff0000u));
    const unsigned l5 = __float_as_uint(v1.y - __uint_as_float(u5 & 0xffff0000u));
    const unsigned l6 = __float_as_uint(v1.z - __uint_as_float(u6 & 0xffff0000u));
    const unsigned l7 = __float_as_uint(v1.w - __uint_as_float(u7 & 0xffff0000u));
    lo.q.x = __builtin_amdgcn_perm(l1, l0, 0x07060302u);
    lo.q.y = __builtin_amdgcn_perm(l3, l2, 0x07060302u);
    lo.q.z = __builtin_amdgcn_perm(l5, l4, 0x07060302u);
    lo.q.w = __builtin_amdgcn_perm(l7, l6, 0x07060302u);
}

// ---------------------------------------------------------------------------
// k_frags: (A) bhi/be1/be2 frags for k_rg; (B) CwE hi/lo frags for k_E;
// (C) u_arr[h] = logf(a[h]) for k_D. grid 384 x 256.
// ---------------------------------------------------------------------------
__global__ __launch_bounds__(256) void k_frags(
    const float* __restrict__ bmat, const float* __restrict__ cmat,
    const float* __restrict__ a,
    unsigned short* __restrict__ bhi, unsigned short* __restrict__ be1,
    unsigned short* __restrict__ be2,
    unsigned short* __restrict__ CwEh, unsigned short* __restrict__ CwEl,
    float* __restrict__ u_arr)
{
    const int t = blockIdx.x * 256 + threadIdx.x;   // 0..98303
    if (t < 512) u_arr[t] = logf(a[t]);
    if (t < 32768) {
        const int j = t & 7, n = (t >> 3) & 15, g = (t >> 7) & 3;
        const int nt = (t >> 9) & 31, kb = (t >> 14) & 1;
        const int h = nt * 16 + n;
        const float v = bmat[(size_t)(kb * 32 + g * 8 + j) * DH_ + h];
        const float u = logf(a[h]);
        bhi[t] = f2b_rne(v);
        be1[t] = f2b_rne(v * u);
        be2[t] = f2b_rne(v * u * u * 0.5f);
    }
    {
        const int j = t & 7;
        const int lane = (t >> 3) & 63;
        const int rem = t >> 9;             // 0..191
        const int nt = rem % 12, kb = rem / 12;
        const int h = kb * 32 + (lane >> 4) * 8 + j;
        const int n = nt * 16 + (lane & 15);
        const int m = n >> 6, o = n & 63;
        const float av = a[h];
        const float u = logf(av);
        const float w = (m == 0) ? av : ((m == 1) ? av * u : av * u * u * 0.5f);
        const float v = w * cmat[(size_t)h * DO_ + o];
        unsigned short hi16 = (unsigned short)(__float_as_uint(v) >> 16);
        float lo = v - __uint_as_float(((unsigned)hi16) << 16);
        CwEh[t] = hi16;
        CwEl[t] = (unsigned short)(__float_as_uint(lo) >> 16);
    }
}

// ---------------------------------------------------------------------------
// k_D (MFMA): D[kpos][o] = sum_h b[i(kpos)][h] * w_p(kpos)[h] * c[h][o].
// grid 12 x 256, output in Dstk B-frag layout (bf16).
// ---------------------------------------------------------------------------
__global__ __launch_bounds__(256) void k_D(
    const float* __restrict__ bmat, const float* __restrict__ cmat,
    const float* __restrict__ u_arr, unsigned short* __restrict__ Dstk)
{
    const int mt   = blockIdx.x;       // 0..11
    const int tid  = threadIdx.x;
    const int lane = tid & 63;
    const int nt   = tid >> 6;         // 0..3
    const int lm   = lane & 15;
    const int lg   = lane >> 4;

    const int kposr = mt * 16 + lm;
    int p, i;
    if (kposr < 128) { i = kposr >> 1; p = kposr & 1; }
    else             { p = 2; i = kposr - 128; }

    f32x4 acc = {0.f, 0.f, 0.f, 0.f};
#pragma unroll
    for (int kb = 0; kb < 16; ++kb) {
        const int h0 = kb * 32 + lg * 8;
        const float4 b0 = *(const float4*)(bmat + (size_t)i * DH_ + h0);
        const float4 b1 = *(const float4*)(bmat + (size_t)i * DH_ + h0 + 4);
        const float4 w0 = *(const float4*)(u_arr + h0);
        const float4 w1 = *(const float4*)(u_arr + h0 + 4);
        const float bv[8] = {b0.x, b0.y, b0.z, b0.w, b1.x, b1.y, b1.z, b1.w};
        const float uv[8] = {w0.x, w0.y, w0.z, w0.w, w1.x, w1.y, w1.z, w1.w};
        U8 af, cf;
        bfv8 ab, cb;
#pragma unroll
        for (int j = 0; j < 8; ++j) {
            const float wp = (p == 0) ? 1.f : ((p == 1) ? uv[j] : uv[j] * uv[j] * 0.5f);
            ab[j] = (__bf16)(bv[j] * wp);
            cb[j] = (__bf16)cmat[(size_t)(h0 + j) * DO_ + nt * 16 + lm];
        }
        af.b = ab; cf.b = cb;
        acc = __builtin_amdgcn_mfma_f32_16x16x32_bf16(af.v, cf.v, acc, 0, 0, 0);
    }

#pragma unroll
    for (int rg = 0; rg < 4; ++rg) {
        const int kpos = mt * 16 + lg * 4 + rg;
        const int o    = nt * 16 + lm;
        Dstk[((size_t)((kpos >> 5) * 4 + (o >> 4)) * 64 + ((kpos >> 3) & 3) * 16 + (o & 15)) * 8 + (kpos & 7)]
            = f2b_rne(acc[rg]);
    }
}

// ---------------------------------------------------------------------------
// k_mom: per-chunk moment reduction over x (streaming). R14-identical.
// ---------------------------------------------------------------------------
__global__ __launch_bounds__(256) void k_mom(
    const float* __restrict__ x, unsigned short* __restrict__ Xm)
{
    const int c   = blockIdx.x;
    const int idx = blockIdx.y * 256 + threadIdx.x;
    const float* xp = x + (size_t)c * 64 * 4096 + idx;

    float m0 = 0.f, m1 = 0.f, m2 = 0.f;
#pragma unroll
    for (int s = 0; s < 64; ++s) {
        const float v = xp[(size_t)s * 4096];
        const float t = (float)(63 - s);
        m0 += v;
        m1 = fmaf(t, v, m1);
        m2 = fmaf(t * t, v, m2);
    }
    __bf16* Xb = (__bf16*)Xm;
    Xb[(size_t)(c * 3 + 0) * 4096 + idx] = (__bf16)m0;
    Xb[(size_t)(c * 3 + 1) * 4096 + idx] = (__bf16)m1;
    Xb[(size_t)(c * 3 + 2) * 4096 + idx] = (__bf16)m2;
}

// ---------------------------------------------------------------------------
// k_rg: r[c][bb][h] = sum_k (u^k/k!)(X_k @ b)[h], one GEMM K=192 folded.
// Re-gridded: (C_, 4 n-quarters) x 256 thr (4 waves x 2 n-tiles) — 256 blocks,
// all CUs busy (was 128 blocks / half the chip).
// ---------------------------------------------------------------------------
__global__ __launch_bounds__(256) void k_rg(
    const unsigned short* __restrict__ Xm,
    const unsigned short* __restrict__ bhi, const unsigned short* __restrict__ be1,
    const unsigned short* __restrict__ be2,
    float* __restrict__ r)
{
    const int c    = blockIdx.x;
    const int nh   = blockIdx.y;            // 0..3 (128-col quarter)
    const int tid  = threadIdx.x;
    const int lane = tid & 63;
    const int w    = tid >> 6;               // 0..3
    const int lm   = lane & 15;
    const int lg   = lane >> 4;

    bf16x8 af[4][6];
#pragma unroll
    for (int mt = 0; mt < 4; ++mt)
#pragma unroll
        for (int kb = 0; kb < 6; ++kb) {
            const int mom = kb >> 1;
            af[mt][kb] = *(const bf16x8*)(Xm + (size_t)(c * 3 + mom) * 4096
                                          + (mt * 16 + lm) * 64 + (kb & 1) * 32 + lg * 8);
        }

    bf16x8 bfr[6][2];
#pragma unroll
    for (int kb = 0; kb < 6; ++kb) {
        const int mom = kb >> 1;
        const unsigned short* base = (mom == 0) ? bhi : (mom == 1) ? be1 : be2;
#pragma unroll
        for (int nt = 0; nt < 2; ++nt) {
            const int ntg = nh * 8 + w * 2 + nt;
            bfr[kb][nt] = *(const bf16x8*)(base + ((size_t)((kb & 1) * 32 + ntg) * 64 + lane) * 8);
        }
    }

    f32x4 acc[4][2];
#pragma unroll
    for (int mt = 0; mt < 4; ++mt)
#pragma unroll
        for (int nt = 0; nt < 2; ++nt) acc[mt][nt] = (f32x4){0.f, 0.f, 0.f, 0.f};

#pragma unroll
    for (int kb = 0; kb < 6; ++kb)
#pragma unroll
        for (int nt = 0; nt < 2; ++nt)
#pragma unroll
            for (int mt = 0; mt < 4; ++mt)
                acc[mt][nt] = __builtin_amdgcn_mfma_f32_16x16x32_bf16(af[mt][kb], bfr[kb][nt], acc[mt][nt], 0, 0, 0);

#pragma unroll
    for (int mt = 0; mt < 4; ++mt)
#pragma unroll
        for (int nt = 0; nt < 2; ++nt)
#pragma unroll
            for (int rg = 0; rg < 4; ++rg) {
                const int bb = mt * 16 + lg * 4 + rg;
                const int h  = nh * 128 + w * 32 + nt * 16 + lm;
                r[((size_t)c * B_ + bb) * DH_ + h] = acc[mt][nt][rg];
            }
}

// ---------------------------------------------------------------------------
// k_scan: sequential scan over chunk aggregates, IN PLACE (r becomes Hst).
// Re-gridded: 256 blocks x 128 threads (was 64 x 512 — only 1/4 of CUs busy).
// ---------------------------------------------------------------------------
__global__ __launch_bounds__(128) void k_scan(
    const float* __restrict__ h0, const float* __restrict__ a,
    float* __restrict__ r, float* __restrict__ hfin)
{
    const int bb  = blockIdx.x >> 2;
    const int hid = (blockIdx.x & 3) * 128 + threadIdx.x;
    const size_t base = (size_t)bb * DH_ + hid;

    float rv[C_];
#pragma unroll
    for (int c = 0; c < C_; ++c) rv[c] = r[(size_t)c * B_ * DH_ + base];

    float h  = h0[base];
    float aL = a[hid];
#pragma unroll
    for (int q = 0; q < 6; ++q) aL = aL * aL;   // a^64

#pragma unroll
    for (int c = 0; c < C_; ++c) {
        r[(size_t)c * B_ * DH_ + base] = h;      // Hst[c]
        h = fmaf(h, aL, rv[c]);
    }
    hfin[base] = h;
}

// ---------------------------------------------------------------------------
// k_E: E[(c*64+bb)][n] = Hst row @ CwE (M=4096, N=192, K=512), hi/lo 3-term.
// grid (4*C_, 3) x 256 threads (768 blocks, 3/CU).
// ---------------------------------------------------------------------------
__global__ __launch_bounds__(256) void k_E(
    const float* __restrict__ Hst,
    const unsigned short* __restrict__ CwEh, const unsigned short* __restrict__ CwEl,
    float* __restrict__ E)
{
    const int bx   = blockIdx.x;
    const int c    = bx >> 2;
    const int ms   = bx & 3;
    const int nb   = blockIdx.y;
    const int tid  = threadIdx.x;
    const int lane = tid & 63;
    const int w    = tid >> 6;
    const int lm   = lane & 15;
    const int lg   = lane >> 4;

    f32x4 acc = {0.f, 0.f, 0.f, 0.f};
    const int ntg = nb * 4 + w;

    for (int kb = 0; kb < 16; ++kb) {
        const float* ap = Hst + (size_t)(c * 64 + ms * 16 + lm) * DH_ + kb * 32 + lg * 8;
        U8 ahi, alo;
        trunc_split8(*(const float4*)ap, *(const float4*)(ap + 4), ahi, alo);
        const size_t fo = ((size_t)(kb * 12 + ntg) * 64 + lane) * 8;
        const bf16x8 bh = *(const bf16x8*)(CwEh + fo);
        const bf16x8 bl = *(const bf16x8*)(CwEl + fo);
        acc = __builtin_amdgcn_mfma_f32_16x16x32_bf16(ahi.v, bh, acc, 0, 0, 0);
        acc = __builtin_amdgcn_mfma_f32_16x16x32_bf16(alo.v, bh, acc, 0, 0, 0);
        acc = __builtin_amdgcn_mfma_f32_16x16x32_bf16(ahi.v, bl, acc, 0, 0, 0);
    }

#pragma unroll
    for (int rg = 0; rg < 4; ++rg) {
        const int row = ms * 16 + lg * 4 + rg;
        E[(size_t)(c * 64 + row) * 192 + ntg * 16 + lm] = acc[rg];
    }
}

// ---------------------------------------------------------------------------
// k_y: per (chunk, batch) block, 512 threads, LDS 30720 B, (512,8) -> 4 blk/CU
// (wave-slot capped at 32). ph2 = parallel two-level prefix scan; ph3 = A @ D
// + E epilogue.
// ---------------------------------------------------------------------------
__global__ __launch_bounds__(512, 8) void k_y(
    const float* __restrict__ x,
    const unsigned short* __restrict__ Dstk,
    const float* __restrict__ E,
    float* __restrict__ y)
{
    __shared__ __align__(16) unsigned short At[64 * 192];  // 24576 B
    __shared__ float Lb[3][8][64];                          // 6144 B

    const int c    = blockIdx.x;
    const int bb   = blockIdx.y;
    const int tid  = threadIdx.x;
    const int lane = tid & 63;
    const int w    = tid >> 6;
    const int lm   = lane & 15;
    const int lg   = lane >> 4;
    const int mp   = w >> 2;
    const int oq   = w & 3;
    const int o    = oq * 16 + lm;

    // ---- ph2: parallel prefix-moment scan ----
    {
        const int i = tid & 63;   // column
        const int j = w;          // 8-step segment

        const float* xp = x + (((size_t)(c * 64 + j * 8)) * 64 + bb) * 64 + i;
        float v[8];
#pragma unroll
        for (int t = 0; t < 8; ++t) v[t] = xp[(size_t)t * 4096];

        float L0 = 0.f, L1 = 0.f, L2 = 0.f;
#pragma unroll
        for (int t = 0; t < 8; ++t) {
            const float sf = (float)(j * 8 + t);
            L0 += v[t];
            L1 = fmaf(sf, v[t], L1);
            L2 = fmaf(sf * sf, v[t], L2);
        }
        Lb[0][j][i] = L0; Lb[1][j][i] = L1; Lb[2][j][i] = L2;
        __syncthreads();

        float S0 = 0.f, S1 = 0.f, S2 = 0.f;
        for (int k = 0; k < j; ++k) {   // j is wave-uniform: no divergence
            S0 += Lb[0][k][i];
            S1 += Lb[1][k][i];
            S2 += Lb[2][k][i];
        }

        char* Ab = (char*)At;
#pragma unroll
        for (int t = 0; t < 8; ++t) {
            const int s = j * 8 + t;
            const float sf = (float)s;
            S0 += v[t];
            S1 = fmaf(sf, v[t], S1);
            S2 = fmaf(sf * sf, v[t], S2);
            const float A0 = S0;
            const float A1 = fmaf(sf, S0, -S1);
            const float A2 = fmaf(sf, fmaf(sf, S0, -2.0f * S1), S2);
            const int f = t << 4;   // (s & 7) == t
            U2 pk; pk.b = __builtin_convertvector((f32x2){A0, A1}, bfv2);
            *(unsigned*)(Ab + ((s * 384 + 4 * i) ^ f)) = pk.u;
            *(__bf16*)(Ab + ((s * 384 + 256 + 2 * i) ^ f)) = (__bf16)A2;
        }
    }
    __syncthreads();

    // E-term loads: latency hides under ph3 MFMAs
    const size_t erow = (size_t)(c * 64 + bb) * 192;
    const float e0 = E[erow + o];
    const float e1 = E[erow + 64 + o];
    const float e2 = E[erow + 128 + o];

    // ---- ph3: y = A @ D + E-term ----
    {
        const int row0 = (mp * 2 + 0) * 16 + lm;
        const int row1 = (mp * 2 + 1) * 16 + lm;
        const int f0 = (row0 & 7) << 4;
        const int f1 = (row1 & 7) << 4;
        const char* Ab = (const char*)At;

        f32x4 acc0 = {0.f, 0.f, 0.f, 0.f};
        f32x4 acc1 = {0.f, 0.f, 0.f, 0.f};

        __builtin_amdgcn_s_setprio(1);
#pragma unroll
        for (int kb = 0; kb < 6; ++kb) {
            const int b2k = kb * 64 + lg * 16;
            const bf16x8 a0 = *(const bf16x8*)(Ab + ((row0 * 384 + b2k) ^ f0));
            const bf16x8 a1 = *(const bf16x8*)(Ab + ((row1 * 384 + b2k) ^ f1));
            const bf16x8 df = *(const bf16x8*)(Dstk + ((size_t)(kb * 4 + oq) * 64 + lane) * 8);
            acc0 = __builtin_amdgcn_mfma_f32_16x16x32_bf16(a0, df, acc0, 0, 0, 0);
            acc1 = __builtin_amdgcn_mfma_f32_16x16x32_bf16(a1, df, acc1, 0, 0, 0);
        }
        __builtin_amdgcn_s_setprio(0);

#pragma unroll
        for (int rg = 0; rg < 4; ++rg) {
            const int sr0 = (mp * 2 + 0) * 16 + lg * 4 + rg;
            const int sr1 = (mp * 2 + 1) * 16 + lg * 4 + rg;
            const float s0f = (float)sr0, s1f = (float)sr1;
            const float y0 = acc0[rg] + fmaf(s0f, fmaf(s0f, e2, e1), e0);
            const float y1 = acc1[rg] + fmaf(s1f, fmaf(s1f, e2, e1), e0);
            y[(((size_t)(c * 64 + sr0)) * 64 + bb) * 64 + o] = y0;
            y[(((size_t)(c * 64 + sr1)) * 64 + bb) * 64 + o] = y1;
        }
    }
}

// ---------------------------------------------------------------------------
extern "C" void kernel_launch(void* const* d_in, const int* in_sizes, int n_in,
                              void* d_out, int out_size, void* d_ws, size_t ws_size,
                              hipStream_t stream) {
    (void)in_sizes; (void)n_in; (void)out_size; (void)ws_size;

    const float* h0 = (const float*)d_in[0];   // [B, DH]
    const float* x  = (const float*)d_in[1];   // [T, B, DI]
    const float* a  = (const float*)d_in[2];   // [DH]
    const float* bm = (const float*)d_in[3];   // [DI, DH]
    const float* cm = (const float*)d_in[4];   // [DH, DO]

    float* out  = (float*)d_out;
    float* hfin = out;                         // [B, DH]
    float* y    = out + (size_t)B_ * DH_;      // [T, B, DO]

    float* r = (float*)d_ws;                   // [C,B,DH] f32 (8 MB), becomes Hst
    unsigned short* bhi  = (unsigned short*)(r + (size_t)C_ * B_ * DH_);
    unsigned short* be1  = bhi + 32768;
    unsigned short* be2  = be1 + 32768;
    unsigned short* CwEh = be2 + 32768;        // 98304
    unsigned short* CwEl = CwEh + 98304;       // 98304
    unsigned short* Dstk = CwEl + 98304;       // 12288
    unsigned short* Xm   = Dstk + 12288;       // [C][3][4096] bf16
    float* E = (float*)(Xm + (size_t)C_ * 3 * 4096);   // [4096][192] f32
    float* u_arr = E + (size_t)4096 * 192;             // [512] f32

    k_frags<<<dim3(384), 256, 0, stream>>>(bm, cm, a, bhi, be1, be2, CwEh, CwEl, u_arr);
    k_D<<<dim3(12), 256, 0, stream>>>(bm, cm, u_arr, Dstk);
    k_mom<<<dim3(C_, 16), 256, 0, stream>>>(x, Xm);
    k_rg<<<dim3(C_, 4), 256, 0, stream>>>(Xm, bhi, be1, be2, r);
    k_scan<<<dim3(256), 128, 0, stream>>>(h0, a, r, hfin);
    k_E<<<dim3(4 * C_, 3), 256, 0, stream>>>(r, CwEh, CwEl, E);
    k_y<<<dim3(C_, B_), 512, 0, stream>>>(x, Dstk, E, y);
}